// Round 15
// baseline (349.320 us; speedup 1.0000x reference)
//
#include <hip/hip_runtime.h>
#include <math.h>
#include <stdint.h>

#define NN 50000
#define DM 128
#define NH 16
#define HC 8
#define NL 3
#define NE 800000
#define MAXDEG 512
#define NRG 1563   // ceil(50000/32) row groups

// CSR-build geometry
#define NB2 782            // coarse buckets of 64 target nodes (782*64=50048)
#define NBLK 256           // blocks in count/scatter phases
#define CNTN (NB2 * NBLK)  // count-matrix entries = 200192
#define SC1 196            // ceil(CNTN/1024)
#define RNG 4              // node ranges for outdeg histogram (16384 nodes each)
#define REP 16             // replicas per range

typedef __attribute__((ext_vector_type(8))) short short8;
typedef __attribute__((ext_vector_type(4))) float f32x4;
typedef __attribute__((ext_vector_type(2))) float f32x2;

static __device__ __forceinline__ unsigned short f2bf(float x) {
    union { float f; unsigned int u; } v; v.f = x;
    unsigned int r = (v.u + 0x7fffu + ((v.u >> 16) & 1u)) >> 16;
    return (unsigned short)r;
}
static __device__ __forceinline__ float bf2f(unsigned short b) {
    union { unsigned int u; float f; } v; v.u = ((unsigned int)b) << 16;
    return v.f;
}

// ======== outdeg histogram: LDS packed-u16, no global atomics ========
__global__ __launch_bounds__(1024) void hist_out_kernel(const int* __restrict__ ei,
                                                        unsigned int* __restrict__ part) {
    __shared__ unsigned int hp[8192];
    int rg = blockIdx.x;
    int rp = blockIdx.y;
    int t = threadIdx.x;
    for (int i = t; i < 8192; i += 1024) hp[i] = 0;
    __syncthreads();
    int lo = rg << 14;
    for (int e = rp * 1024 + t; e < NE; e += REP * 1024) {
        int s = ei[e] - lo;
        if ((unsigned)s < 16384u)
            atomicAdd(&hp[s >> 1], (s & 1) ? 0x10000u : 1u);
    }
    __syncthreads();
    unsigned int* pp = part + (size_t)(rg * REP + rp) * 8192;
    for (int i = t; i < 8192; i += 1024) pp[i] = hp[i];
}
__global__ __launch_bounds__(256) void hist_reduce_kernel(const unsigned int* __restrict__ part,
                                                          int* __restrict__ outdeg) {
    int wd = blockIdx.x * 256 + threadIdx.x;
    if (wd >= 25000) return;
    int rg = wd >> 13, lw = wd & 8191;
    unsigned int sum = 0;
#pragma unroll
    for (int r = 0; r < REP; r++)
        sum += part[(size_t)(rg * REP + r) * 8192 + lw];
    outdeg[2 * wd] = sum & 0xffff;
    if (2 * wd + 1 < NN) outdeg[2 * wd + 1] = sum >> 16;
}

// ======== CSR build phase 1: per-(block,bucket) counts ========
__global__ __launch_bounds__(256) void p1_count_kernel(const int* __restrict__ ei,
                                                       int* __restrict__ cnt) {
    __shared__ int hh[NB2];
    int t = threadIdx.x, blk = blockIdx.x;
    for (int b = t; b < NB2; b += 256) hh[b] = 0;
    __syncthreads();
    for (int e = blk * 256 + t; e < NE; e += NBLK * 256)
        atomicAdd(&hh[ei[NE + e] >> 6], 1);
    __syncthreads();
    for (int b = t; b < NB2; b += 256) cnt[b * NBLK + blk] = hh[b];
}

// ======== generic 3-kernel exclusive scan ========
__global__ __launch_bounds__(1024) void gscan1_kernel(int* __restrict__ data,
                                                      int* __restrict__ bsum, int n) {
    __shared__ int sd[1024];
    int t = threadIdx.x;
    int i = blockIdx.x * 1024 + t;
    int val = (i < n) ? data[i] : 0;
    sd[t] = val;
    __syncthreads();
    for (int d = 1; d < 1024; d <<= 1) {
        int x = (t >= d) ? sd[t - d] : 0;
        __syncthreads();
        sd[t] += x;
        __syncthreads();
    }
    if (i < n) data[i] = sd[t] - val;
    if (t == 1023) bsum[blockIdx.x] = sd[1023];
}
__global__ void gscan2_kernel(const int* __restrict__ bsum, int* __restrict__ bpre, int nb) {
    int run = 0;
    for (int i = 0; i < nb; i++) { bpre[i] = run; run += bsum[i]; }
}
__global__ __launch_bounds__(1024) void gscan3_kernel(int* __restrict__ data,
                                                      const int* __restrict__ bpre, int n) {
    int i = blockIdx.x * 1024 + threadIdx.x;
    if (i < n) data[i] += bpre[blockIdx.x];
}

// ======== CSR phase 3: rank-scatter into bucket-grouped tmp ========
__global__ __launch_bounds__(256) void p3_scatter_kernel(const int* __restrict__ ei,
                                                         const int* __restrict__ cnt,
                                                         int* __restrict__ tmp) {
    __shared__ int hh[NB2];
    int t = threadIdx.x, blk = blockIdx.x;
    for (int b = t; b < NB2; b += 256) hh[b] = cnt[b * NBLK + blk];
    __syncthreads();
    for (int e = blk * 256 + t; e < NE; e += NBLK * 256) {
        int s = ei[e], tg = ei[NE + e];
        int pos = atomicAdd(&hh[tg >> 6], 1);
        tmp[pos] = ((tg & 63) << 16) | s;
    }
}

// ======== CSR phase 4: per-bucket fine CSR (off, indeg, srcs) ========
__global__ __launch_bounds__(256) void p4_fine_kernel(const int* __restrict__ tmp,
                                                      const int* __restrict__ cnt,
                                                      int* __restrict__ off,
                                                      int* __restrict__ indeg,
                                                      int* __restrict__ srcs) {
    __shared__ int c64[64], x64[64], cur[64];
    int b = blockIdx.x, t = threadIdx.x;
    int e0 = cnt[b * NBLK];
    int e1 = (b == NB2 - 1) ? NE : cnt[(b + 1) * NBLK];
    if (t < 64) c64[t] = 0;
    __syncthreads();
    for (int i = e0 + t; i < e1; i += 256) atomicAdd(&c64[(tmp[i] >> 16) & 63], 1);
    __syncthreads();
    if (t == 0) {
        int run = 0;
        for (int j = 0; j < 64; j++) { x64[j] = run; cur[j] = e0 + run; run += c64[j]; }
    }
    __syncthreads();
    if (t < 64) {
        int node = b * 64 + t;
        if (node <= NN) off[node] = e0 + x64[t];
        if (node < NN) indeg[node] = c64[t];
    }
    __syncthreads();
    for (int i = e0 + t; i < e1; i += 256) {
        int w = tmp[i];
        int pos = atomicAdd(&cur[(w >> 16) & 63], 1);
        srcs[pos] = w & 0xffff;
    }
}

// -------- weight prep: 13 matrices -> bf16 transposed [col][k] ------------
__global__ __launch_bounds__(256) void wprep_kernel(const float* __restrict__ Wq,
                                                    const float* __restrict__ Wk,
                                                    const float* __restrict__ Wv,
                                                    const float* __restrict__ Ws,
                                                    const float* __restrict__ Win,
                                                    unsigned short* __restrict__ Wt) {
    __shared__ unsigned short lds[128 * 130];
    int bid = blockIdx.x;
    const float* W;
    if (bid == 12) {
        W = Win;
    } else {
        int l = bid >> 2, m = bid & 3;
        W = (m == 0 ? Wq : m == 1 ? Wk : m == 2 ? Wv : Ws) + (size_t)l * DM * DM;
    }
    unsigned short* out = Wt + (size_t)bid * DM * DM;
    int t = threadIdx.x;
    for (int i = t; i < DM * DM; i += 256) {
        int kk = i >> 7, c = i & 127;
        lds[kk * 130 + c] = f2bf(W[i]);
    }
    __syncthreads();
    for (int o = t; o < DM * DM; o += 256) {
        int c = o >> 7, kk = o & 127;
        out[o] = lds[kk * 130 + c];
    }
}

// ---------------- x cast fp32 -> bf16 ----------------
__global__ __launch_bounds__(256) void xcast_kernel(const float* __restrict__ x,
                                                    unsigned short* __restrict__ xb) {
    int i = blockIdx.x * 256 + threadIdx.x;
    float4 xv = ((const float4*)x)[i];
    ushort4 o;
    o.x = f2bf(xv.x); o.y = f2bf(xv.y); o.z = f2bf(xv.z); o.w = f2bf(xv.w);
    ((ushort4*)xb)[i] = o;
}

// ------- input GEMM via MFMA (swapped operands) + embeddings
//         + FUSED layer-0 LayerNorm -> hn bf16 (cross-wave LDS reduce) -----
__global__ __launch_bounds__(256) void gemm_in_mfma(const unsigned short* __restrict__ xb,
                                                    const unsigned short* __restrict__ Wt,
                                                    const float* __restrict__ b,
                                                    const float* __restrict__ in_emb,
                                                    const float* __restrict__ out_emb,
                                                    const int* __restrict__ indeg,
                                                    const int* __restrict__ outdeg,
                                                    float* __restrict__ h,
                                                    const float* __restrict__ nsc,
                                                    const float* __restrict__ nbi,
                                                    unsigned short* __restrict__ hn) {
    __shared__ f32x2 pp[4][2][16];   // [wave][nt][lr] partial (sum, sumsq)
    int w = threadIdx.x >> 6;
    int l = threadIdx.x & 63;
    int lr = l & 15, lc = l >> 4;
    int colbase = (w & 1) * 64;
    int rhalf = w >> 1;

    short8 bfrag[4][4];
#pragma unroll
    for (int ct = 0; ct < 4; ct++) {
        const unsigned short* bp = Wt + (size_t)(colbase + ct * 16 + lr) * DM;
#pragma unroll
        for (int kk = 0; kk < 4; kk++)
            bfrag[ct][kk] = *(const short8*)(bp + kk * 32 + lc * 8);
    }

    for (int it = blockIdx.x; it < 782; it += gridDim.x) {
        int rg = it * 2 + rhalf;
        bool act = (rg < NRG);
        int n0 = rg * 32;
        float hval[2][16];
        float s2[2], q2[2];
        s2[0] = s2[1] = q2[0] = q2[1] = 0.f;

        if (act) {
            short8 afrag[2][4];
#pragma unroll
            for (int nt = 0; nt < 2; nt++) {
                int row = n0 + nt * 16 + lr;
                if (row >= NN) row = NN - 1;
                const unsigned short* ap = xb + (size_t)row * DM;
#pragma unroll
                for (int kk = 0; kk < 4; kk++)
                    afrag[nt][kk] = *(const short8*)(ap + kk * 32 + lc * 8);
            }
            f32x4 acc[4][2];
#pragma unroll
            for (int ct = 0; ct < 4; ct++)
#pragma unroll
                for (int nt = 0; nt < 2; nt++)
                    acc[ct][nt] = (f32x4){0.f, 0.f, 0.f, 0.f};
#pragma unroll
            for (int kk = 0; kk < 4; kk++)
#pragma unroll
                for (int ct = 0; ct < 4; ct++)
#pragma unroll
                    for (int nt = 0; nt < 2; nt++)
                        acc[ct][nt] = __builtin_amdgcn_mfma_f32_16x16x32_bf16(
                            bfrag[ct][kk], afrag[nt][kk], acc[ct][nt], 0, 0, 0);
#pragma unroll
            for (int nt = 0; nt < 2; nt++) {
                int node = n0 + nt * 16 + lr;
                int nodec = (node < NN) ? node : (NN - 1);
                int id = min(indeg[nodec], MAXDEG);
                int od = min(outdeg[nodec], MAXDEG);
                float s = 0.f, sq = 0.f;
#pragma unroll
                for (int ct = 0; ct < 4; ct++) {
                    int ch = colbase + ct * 16 + lc * 4;
                    float4 bb = *(const float4*)(b + ch);
                    float4 ie = *(const float4*)(in_emb + (size_t)id * DM + ch);
                    float4 oe = *(const float4*)(out_emb + (size_t)od * DM + ch);
                    float4 o;
                    o.x = acc[ct][nt][0] + bb.x + ie.x + oe.x;
                    o.y = acc[ct][nt][1] + bb.y + ie.y + oe.y;
                    o.z = acc[ct][nt][2] + bb.z + ie.z + oe.z;
                    o.w = acc[ct][nt][3] + bb.w + ie.w + oe.w;
                    hval[nt][ct * 4 + 0] = o.x;
                    hval[nt][ct * 4 + 1] = o.y;
                    hval[nt][ct * 4 + 2] = o.z;
                    hval[nt][ct * 4 + 3] = o.w;
                    s += o.x + o.y + o.z + o.w;
                    sq += o.x * o.x + o.y * o.y + o.z * o.z + o.w * o.w;
                    if (node < NN)
                        *(float4*)(h + (size_t)node * DM + ch) = o;
                }
                s += __shfl_xor(s, 16); s += __shfl_xor(s, 32);
                sq += __shfl_xor(sq, 16); sq += __shfl_xor(sq, 32);
                s2[nt] = s; q2[nt] = sq;
            }
        }
        __syncthreads();
        if (act && lc == 0) {
            pp[w][0][lr] = (f32x2){s2[0], q2[0]};
            pp[w][1][lr] = (f32x2){s2[1], q2[1]};
        }
        __syncthreads();
        if (act) {
#pragma unroll
            for (int nt = 0; nt < 2; nt++) {
                f32x2 po = pp[w ^ 1][nt][lr];
                float S = s2[nt] + po.x;
                float Q = q2[nt] + po.y;
                float mu = S * (1.f / 128.f);
                float var = Q * (1.f / 128.f) - mu * mu;
                float rstd = rsqrtf(var + 1e-5f);
                int node = n0 + nt * 16 + lr;
                if (node < NN) {
#pragma unroll
                    for (int ct = 0; ct < 4; ct++) {
                        int ch = colbase + ct * 16 + lc * 4;
                        float4 scv = *(const float4*)(nsc + ch);
                        float4 biv = *(const float4*)(nbi + ch);
                        ushort4 o;
                        o.x = f2bf((hval[nt][ct * 4 + 0] - mu) * rstd * scv.x + biv.x);
                        o.y = f2bf((hval[nt][ct * 4 + 1] - mu) * rstd * scv.y + biv.y);
                        o.z = f2bf((hval[nt][ct * 4 + 2] - mu) * rstd * scv.z + biv.z);
                        o.w = f2bf((hval[nt][ct * 4 + 3] - mu) * rstd * scv.w + biv.w);
                        *(ushort4*)(hn + (size_t)node * DM + ch) = o;
                    }
                }
            }
        }
    }
}

// ------- fused Q/K/V/skip GEMM via bf16 MFMA; LDS-staged A; swapped-operand
//         epilogue; kv8: per node, 8B group g = [k 4g..4g+3 | v 4g..4g+3] ---
__global__ __launch_bounds__(512) void gemm_qkvs_mfma(const unsigned short* __restrict__ hn,
                                                      const unsigned short* __restrict__ Wt,  // [512][128]
                                                      const float* __restrict__ bq, const float* __restrict__ bk,
                                                      const float* __restrict__ bv, const float* __restrict__ bs,
                                                      unsigned short* __restrict__ q,
                                                      unsigned char* __restrict__ kv8,
                                                      unsigned short* __restrict__ xrb) {
    __shared__ uint4 alds4[512];    // 32 rows x 128 ch bf16 = 8 KB
    unsigned short* alds = (unsigned short*)alds4;

    int w = threadIdx.x >> 6;       // 0..7
    int l = threadIdx.x & 63;
    int lr = l & 15, lc = l >> 4;
    int colbase = w * 64;
    int m = w >> 1;                 // wave-uniform: 0=q 1=k 2=v 3=skip
    int cmbase = (w & 1) * 64;
    int t = threadIdx.x;
    int ar = t >> 4;
    int ag = t & 15;
    int agx = ag ^ (ar & 7);

    const float* bptr = (m == 0 ? bq : m == 1 ? bk : m == 2 ? bv : bs);
    short8 bfrag[4][4];
    float biasv[4][4];
#pragma unroll
    for (int ct = 0; ct < 4; ct++) {
        int col = colbase + ct * 16 + lr;
        const unsigned short* bp = Wt + (size_t)col * DM;
#pragma unroll
        for (int kk = 0; kk < 4; kk++)
            bfrag[ct][kk] = *(const short8*)(bp + kk * 32 + lc * 8);
#pragma unroll
        for (int j = 0; j < 4; j++)
            biasv[ct][j] = bptr[cmbase + ct * 16 + lc * 4 + j];
    }

    for (int rg = blockIdx.x; rg < NRG; rg += gridDim.x) {
        int n0 = rg * 32;
        int grow = n0 + ar;
        if (grow >= NN) grow = NN - 1;
        uint4 av = *(const uint4*)(hn + (size_t)grow * DM + ag * 8);
        __syncthreads();
        alds4[ar * 16 + agx] = av;
        __syncthreads();

        short8 afrag[2][4];
#pragma unroll
        for (int nt = 0; nt < 2; nt++)
#pragma unroll
            for (int kk = 0; kk < 4; kk++) {
                int g = kk * 4 + lc;
                int gx = g ^ (lr & 7);
                afrag[nt][kk] = *(const short8*)(alds + (nt * 16 + lr) * 128 + gx * 8);
            }

        f32x4 acc[4][2];
#pragma unroll
        for (int ct = 0; ct < 4; ct++)
#pragma unroll
            for (int nt = 0; nt < 2; nt++)
                acc[ct][nt] = (f32x4){0.f, 0.f, 0.f, 0.f};
#pragma unroll
        for (int kk = 0; kk < 4; kk++)
#pragma unroll
            for (int ct = 0; ct < 4; ct++)
#pragma unroll
                for (int nt = 0; nt < 2; nt++)
                    acc[ct][nt] = __builtin_amdgcn_mfma_f32_16x16x32_bf16(
                        bfrag[ct][kk], afrag[nt][kk], acc[ct][nt], 0, 0, 0);

        if (m == 0 || m == 3) {
            unsigned short* dst = (m == 0) ? q : xrb;
#pragma unroll
            for (int nt = 0; nt < 2; nt++) {
                int node = n0 + nt * 16 + lr;
                if (node < NN) {
#pragma unroll
                    for (int ct = 0; ct < 4; ct++) {
                        int ch = cmbase + ct * 16 + lc * 4;
                        ushort4 st;
                        st.x = f2bf(acc[ct][nt][0] + biasv[ct][0]);
                        st.y = f2bf(acc[ct][nt][1] + biasv[ct][1]);
                        st.z = f2bf(acc[ct][nt][2] + biasv[ct][2]);
                        st.w = f2bf(acc[ct][nt][3] + biasv[ct][3]);
                        *(ushort4*)(dst + (size_t)node * DM + ch) = st;
                    }
                }
            }
        } else {
            unsigned char* base = kv8 + ((m == 1) ? 0 : 4);
#pragma unroll
            for (int nt = 0; nt < 2; nt++) {
                int node = n0 + nt * 16 + lr;
                if (node < NN) {
#pragma unroll
                    for (int ct = 0; ct < 4; ct++) {
                        int ch = cmbase + ct * 16 + lc * 4;
                        int wd = __builtin_amdgcn_cvt_pk_fp8_f32(
                            acc[ct][nt][0] + biasv[ct][0],
                            acc[ct][nt][1] + biasv[ct][1], 0, false);
                        wd = __builtin_amdgcn_cvt_pk_fp8_f32(
                            acc[ct][nt][2] + biasv[ct][2],
                            acc[ct][nt][3] + biasv[ct][3], wd, true);
                        *(unsigned int*)(base + (size_t)node * 256 + (ch >> 2) * 8) =
                            (unsigned int)wd;
                    }
                }
            }
        }
    }
}

// ---- fused attention (r10 structure + packed f32x2 math + 32-bit gather
//      offsets): one wave per node; 4 ch/lane over 32 lanes; chunk-16
//      unchecked + masked tail; beta gate + fused next-layer/final LN -----
__global__ __launch_bounds__(256) void attn_fused_kernel(const int* __restrict__ off,
                                                         const int* __restrict__ srcs,
                                                         const unsigned short* __restrict__ q,
                                                         const unsigned char* __restrict__ kv8,
                                                         const unsigned short* __restrict__ xrb,
                                                         const float* __restrict__ Wb,
                                                         float* __restrict__ h,
                                                         const float* __restrict__ nsc,
                                                         const float* __restrict__ nbi,
                                                         unsigned short* __restrict__ hn_out,
                                                         const float* __restrict__ fsc,
                                                         const float* __restrict__ fbi,
                                                         float* __restrict__ fout) {
    int wv = threadIdx.x >> 6;    // 4 nodes per block
    int L = threadIdx.x & 63;
    int half = L >> 5, L5 = L & 31;
    int n = blockIdx.x * 4 + wv;
    int o0 = off[n], o1 = off[n + 1];
    int c4 = L5 * 4;
    unsigned co = (unsigned)(L5 * 8);
    const float isq = 0.35355339059f;  // 1/sqrt(8)

    ushort4 qu = *(const ushort4*)(q + (size_t)n * DM + c4);
    f32x2 q01 = {bf2f(qu.x) * isq, bf2f(qu.y) * isq};
    f32x2 q23 = {bf2f(qu.z) * isq, bf2f(qu.w) * isq};

    float den = 0.f;
    f32x2 ac01 = {0.f, 0.f}, ac23 = {0.f, 0.f};
    int p = o0;
    // ---- full chunks: no bounds checks anywhere ----
    for (; p + 16 <= o1; p += 16) {
        unsigned oj[8];
#pragma unroll
        for (int j = 0; j < 8; j++)
            oj[j] = (unsigned)srcs[p + 2 * j + half] * 256u + co;
        uint2 uu[8];
#pragma unroll
        for (int j = 0; j < 8; j++)
            uu[j] = *(const uint2*)(kv8 + oj[j]);
#pragma unroll
        for (int j = 0; j < 8; j++) {
            f32x2 k01 = __builtin_amdgcn_cvt_pk_f32_fp8(uu[j].x, false);
            f32x2 k23 = __builtin_amdgcn_cvt_pk_f32_fp8(uu[j].x, true);
            f32x2 dd = q01 * k01 + q23 * k23;       // packed FMA
            float d = dd.x + dd.y;
            d += __shfl_xor(d, 1);  // 8-channel head dot (2 lanes/head)
            float e2 = __expf(d);
            f32x2 v01 = __builtin_amdgcn_cvt_pk_f32_fp8(uu[j].y, false);
            f32x2 v23 = __builtin_amdgcn_cvt_pk_f32_fp8(uu[j].y, true);
            f32x2 ee = {e2, e2};
            ac01 += ee * v01;
            ac23 += ee * v23;
            den += e2;
        }
    }
    // ---- masked tail chunk (0..15 remaining edges) ----
    if (p < o1) {
        unsigned oj[8];
        int ev[8];
#pragma unroll
        for (int j = 0; j < 8; j++) {
            int e = p + 2 * j + half;
            ev[8 - 8 + j] = e;
            oj[j] = (e < o1) ? ((unsigned)srcs[e] * 256u + co) : co;
        }
        uint2 uu[8];
#pragma unroll
        for (int j = 0; j < 8; j++)
            uu[j] = *(const uint2*)(kv8 + oj[j]);
#pragma unroll
        for (int j = 0; j < 8; j++) {
            f32x2 k01 = __builtin_amdgcn_cvt_pk_f32_fp8(uu[j].x, false);
            f32x2 k23 = __builtin_amdgcn_cvt_pk_f32_fp8(uu[j].x, true);
            f32x2 dd = q01 * k01 + q23 * k23;
            float d = dd.x + dd.y;
            d += __shfl_xor(d, 1);
            float e2 = (ev[j] < o1) ? __expf(d) : 0.f;
            f32x2 v01 = __builtin_amdgcn_cvt_pk_f32_fp8(uu[j].y, false);
            f32x2 v23 = __builtin_amdgcn_cvt_pk_f32_fp8(uu[j].y, true);
            f32x2 ee = {e2, e2};
            ac01 += ee * v01;
            ac23 += ee * v23;
            den += e2;
        }
    }
    // combine the two half-wave edge partitions (same channels)
    float a0 = ac01.x, a1 = ac01.y, a2 = ac23.x, a3 = ac23.y;
    den += __shfl_xor(den, 32);
    a0 += __shfl_xor(a0, 32);
    a1 += __shfl_xor(a1, 32);
    a2 += __shfl_xor(a2, 32);
    a3 += __shfl_xor(a3, 32);

    float inv = (den > 0.f) ? 1.f / den : 0.f;
    float o0v = a0 * inv, o1v = a1 * inv, o2v = a2 * inv, o3v = a3 * inv;

    ushort4 xu = *(const ushort4*)(xrb + (size_t)n * DM + c4);
    float x0 = bf2f(xu.x), x1 = bf2f(xu.y), x2 = bf2f(xu.z), x3 = bf2f(xu.w);
    float c = o0v * Wb[c4] + o1v * Wb[c4 + 1] + o2v * Wb[c4 + 2] + o3v * Wb[c4 + 3]
            + x0 * Wb[DM + c4] + x1 * Wb[DM + c4 + 1]
            + x2 * Wb[DM + c4 + 2] + x3 * Wb[DM + c4 + 3]
            + (o0v - x0) * Wb[2 * DM + c4] + (o1v - x1) * Wb[2 * DM + c4 + 1]
            + (o2v - x2) * Wb[2 * DM + c4 + 2] + (o3v - x3) * Wb[2 * DM + c4 + 3];
    if (half) c = 0.f;   // avoid double-count: channels duplicated across halves
#pragma unroll
    for (int d2 = 32; d2; d2 >>= 1) c += __shfl_xor(c, d2);
    float beta = 1.f / (1.f + __expf(-c));

    size_t idx = (size_t)n * DM + c4;
    float4 hv = *(const float4*)(h + idx);
    hv.x += beta * x0 + (1.f - beta) * o0v;
    hv.y += beta * x1 + (1.f - beta) * o1v;
    hv.z += beta * x2 + (1.f - beta) * o2v;
    hv.w += beta * x3 + (1.f - beta) * o3v;

    if (fout) {
        // final LayerNorm fused -> fp32 d_out
        float s = hv.x + hv.y + hv.z + hv.w;
#pragma unroll
        for (int d2 = 16; d2; d2 >>= 1) s += __shfl_xor(s, d2);
        float mu = s * (1.f / 128.f);
        float d0 = hv.x - mu, d1 = hv.y - mu, d2_ = hv.z - mu, d3 = hv.w - mu;
        float vs = d0 * d0 + d1 * d1 + d2_ * d2_ + d3 * d3;
#pragma unroll
        for (int d2 = 16; d2; d2 >>= 1) vs += __shfl_xor(vs, d2);
        float rstd = rsqrtf(vs * (1.f / 128.f) + 1e-5f);
        if (half == 0) {
            float4 scv = *(const float4*)(fsc + c4);
            float4 biv = *(const float4*)(fbi + c4);
            float4 o;
            o.x = d0 * rstd * scv.x + biv.x;
            o.y = d1 * rstd * scv.y + biv.y;
            o.z = d2_ * rstd * scv.z + biv.z;
            o.w = d3 * rstd * scv.w + biv.w;
            *(float4*)(fout + idx) = o;
        }
    } else {
        if (half == 0) *(float4*)(h + idx) = hv;
        // next-layer LayerNorm fused -> hn bf16
        float s = hv.x + hv.y + hv.z + hv.w;
#pragma unroll
        for (int d2 = 16; d2; d2 >>= 1) s += __shfl_xor(s, d2);
        float mu = s * (1.f / 128.f);
        float d0 = hv.x - mu, d1 = hv.y - mu, d2_ = hv.z - mu, d3 = hv.w - mu;
        float vs = d0 * d0 + d1 * d1 + d2_ * d2_ + d3 * d3;
#pragma unroll
        for (int d2 = 16; d2; d2 >>= 1) vs += __shfl_xor(vs, d2);
        float rstd = rsqrtf(vs * (1.f / 128.f) + 1e-5f);
        if (half == 0) {
            float4 scv = *(const float4*)(nsc + c4);
            float4 biv = *(const float4*)(nbi + c4);
            ushort4 o;
            o.x = f2bf(d0 * rstd * scv.x + biv.x);
            o.y = f2bf(d1 * rstd * scv.y + biv.y);
            o.z = f2bf(d2_ * rstd * scv.z + biv.z);
            o.w = f2bf(d3 * rstd * scv.w + biv.w);
            *(ushort4*)(hn_out + idx) = o;
        }
    }
}

static inline char* alignup(char* p) {
    return (char*)(((uintptr_t)p + 255) & ~(uintptr_t)255);
}

extern "C" void kernel_launch(void* const* d_in, const int* in_sizes, int n_in,
                              void* d_out, int out_size, void* d_ws, size_t ws_size,
                              hipStream_t stream) {
    const float* x       = (const float*)d_in[0];
    const int*   ei      = (const int*)d_in[1];
    const float* W_in    = (const float*)d_in[2];
    const float* b_in    = (const float*)d_in[3];
    const float* in_emb  = (const float*)d_in[4];
    const float* out_emb = (const float*)d_in[5];
    const float* ln_sc   = (const float*)d_in[6];
    const float* ln_bi   = (const float*)d_in[7];
    const float* Wq      = (const float*)d_in[8];
    const float* bq      = (const float*)d_in[9];
    const float* Wk      = (const float*)d_in[10];
    const float* bk      = (const float*)d_in[11];
    const float* Wv      = (const float*)d_in[12];
    const float* bv      = (const float*)d_in[13];
    const float* Wsk     = (const float*)d_in[14];
    const float* bsk     = (const float*)d_in[15];
    const float* Wbeta   = (const float*)d_in[16];
    const float* fn_sc   = (const float*)d_in[17];
    const float* fn_bi   = (const float*)d_in[18];

    char* w = (char*)d_ws;
    int* indeg  = (int*)w; w = alignup(w + (size_t)NN * 4);
    int* outdeg = (int*)w; w = alignup(w + (size_t)NN * 4);
    int* off    = (int*)w; w = alignup(w + (size_t)(NN + 1) * 4);
    int* srcs   = (int*)w; w = alignup(w + (size_t)NE * 4);
    int* tmp    = (int*)w; w = alignup(w + (size_t)NE * 4);
    int* cnt    = (int*)w; w = alignup(w + (size_t)CNTN * 4);
    int* bsum   = (int*)w; w = alignup(w + (size_t)SC1 * 4);
    int* bpre   = (int*)w; w = alignup(w + (size_t)SC1 * 4);
    unsigned int* hpart = (unsigned int*)w; w = alignup(w + (size_t)RNG * REP * 8192 * 4);
    float* h    = (float*)w; w = alignup(w + (size_t)NN * DM * 4);
    unsigned short* hn  = (unsigned short*)w; w = alignup(w + (size_t)NN * DM * 2);
    unsigned short* q   = (unsigned short*)w; w = alignup(w + (size_t)NN * DM * 2);
    unsigned short* xrb = (unsigned short*)w; w = alignup(w + (size_t)NN * DM * 2);
    unsigned char*  kv8 = (unsigned char*)w;  w = alignup(w + (size_t)NN * 256);
    unsigned short* xb  = (unsigned short*)w; w = alignup(w + (size_t)NN * DM * 2);
    unsigned short* Wt  = (unsigned short*)w; w = alignup(w + (size_t)13 * DM * DM * 2);

    // ---- CSR build (no global atomics) ----
    hist_out_kernel<<<dim3(RNG, REP), 1024, 0, stream>>>(ei, hpart);
    hist_reduce_kernel<<<98, 256, 0, stream>>>(hpart, outdeg);
    p1_count_kernel<<<NBLK, 256, 0, stream>>>(ei, cnt);
    gscan1_kernel<<<SC1, 1024, 0, stream>>>(cnt, bsum, CNTN);
    gscan2_kernel<<<1, 1, 0, stream>>>(bsum, bpre, SC1);
    gscan3_kernel<<<SC1, 1024, 0, stream>>>(cnt, bpre, CNTN);
    p3_scatter_kernel<<<NBLK, 256, 0, stream>>>(ei, cnt, tmp);
    p4_fine_kernel<<<NB2, 256, 0, stream>>>(tmp, cnt, off, indeg, srcs);

    wprep_kernel<<<13, 256, 0, stream>>>(Wq, Wk, Wv, Wsk, W_in, Wt);
    xcast_kernel<<<NN * DM / 4 / 256, 256, 0, stream>>>(x, xb);

    gemm_in_mfma<<<391, 256, 0, stream>>>(xb, Wt + (size_t)12 * DM * DM, b_in,
                                          in_emb, out_emb, indeg, outdeg, h,
                                          ln_sc, ln_bi, hn);
    for (int l = 0; l < NL; l++) {
        gemm_qkvs_mfma<<<391, 512, 0, stream>>>(hn,
            Wt + (size_t)l * 4 * DM * DM,
            bq + l * DM, bk + l * DM, bv + l * DM, bsk + l * DM,
            q, kv8, xrb);
        bool last = (l == NL - 1);
        attn_fused_kernel<<<NN / 4, 256, 0, stream>>>(off, srcs, q, kv8, xrb,
            Wbeta + (size_t)l * 3 * DM, h,
            last ? (const float*)nullptr : ln_sc + (l + 1) * DM,
            last ? (const float*)nullptr : ln_bi + (l + 1) * DM,
            last ? (unsigned short*)nullptr : hn,
            last ? fn_sc : (const float*)nullptr,
            last ? fn_bi : (const float*)nullptr,
            last ? (float*)d_out : (float*)nullptr);
    }
}

// Round 16
// 337.520 us; speedup vs baseline: 1.0350x; 1.0350x over previous
//
#include <hip/hip_runtime.h>
#include <math.h>
#include <stdint.h>

#define NN 50000
#define DM 128
#define NH 16
#define HC 8
#define NL 3
#define NE 800000
#define MAXDEG 512
#define NRG 1563   // ceil(50000/32) row groups

// CSR-build geometry
#define NB2 782            // coarse buckets of 64 target nodes (782*64=50048)
#define NBLK 256           // blocks in count/scatter phases
#define CNTN (NB2 * NBLK)  // count-matrix entries = 200192
#define SC1 196            // ceil(CNTN/1024)
#define RNG 4              // node ranges for outdeg histogram (16384 nodes each)
#define REP 16             // replicas per range

typedef __attribute__((ext_vector_type(8))) short short8;
typedef __attribute__((ext_vector_type(4))) float f32x4;
typedef __attribute__((ext_vector_type(2))) float f32x2;

static __device__ __forceinline__ unsigned short f2bf(float x) {
    union { float f; unsigned int u; } v; v.f = x;
    unsigned int r = (v.u + 0x7fffu + ((v.u >> 16) & 1u)) >> 16;
    return (unsigned short)r;
}
static __device__ __forceinline__ float bf2f(unsigned short b) {
    union { unsigned int u; float f; } v; v.u = ((unsigned int)b) << 16;
    return v.f;
}

// ======== outdeg histogram: LDS packed-u16, no global atomics ========
__global__ __launch_bounds__(1024) void hist_out_kernel(const int* __restrict__ ei,
                                                        unsigned int* __restrict__ part) {
    __shared__ unsigned int hp[8192];
    int rg = blockIdx.x;
    int rp = blockIdx.y;
    int t = threadIdx.x;
    for (int i = t; i < 8192; i += 1024) hp[i] = 0;
    __syncthreads();
    int lo = rg << 14;
    for (int e = rp * 1024 + t; e < NE; e += REP * 1024) {
        int s = ei[e] - lo;
        if ((unsigned)s < 16384u)
            atomicAdd(&hp[s >> 1], (s & 1) ? 0x10000u : 1u);
    }
    __syncthreads();
    unsigned int* pp = part + (size_t)(rg * REP + rp) * 8192;
    for (int i = t; i < 8192; i += 1024) pp[i] = hp[i];
}
__global__ __launch_bounds__(256) void hist_reduce_kernel(const unsigned int* __restrict__ part,
                                                          int* __restrict__ outdeg) {
    int wd = blockIdx.x * 256 + threadIdx.x;
    if (wd >= 25000) return;
    int rg = wd >> 13, lw = wd & 8191;
    unsigned int sum = 0;
#pragma unroll
    for (int r = 0; r < REP; r++)
        sum += part[(size_t)(rg * REP + r) * 8192 + lw];
    outdeg[2 * wd] = sum & 0xffff;
    if (2 * wd + 1 < NN) outdeg[2 * wd + 1] = sum >> 16;
}

// ======== CSR build phase 1: per-(block,bucket) counts ========
__global__ __launch_bounds__(256) void p1_count_kernel(const int* __restrict__ ei,
                                                       int* __restrict__ cnt) {
    __shared__ int hh[NB2];
    int t = threadIdx.x, blk = blockIdx.x;
    for (int b = t; b < NB2; b += 256) hh[b] = 0;
    __syncthreads();
    for (int e = blk * 256 + t; e < NE; e += NBLK * 256)
        atomicAdd(&hh[ei[NE + e] >> 6], 1);
    __syncthreads();
    for (int b = t; b < NB2; b += 256) cnt[b * NBLK + blk] = hh[b];
}

// ======== generic 3-kernel exclusive scan ========
__global__ __launch_bounds__(1024) void gscan1_kernel(int* __restrict__ data,
                                                      int* __restrict__ bsum, int n) {
    __shared__ int sd[1024];
    int t = threadIdx.x;
    int i = blockIdx.x * 1024 + t;
    int val = (i < n) ? data[i] : 0;
    sd[t] = val;
    __syncthreads();
    for (int d = 1; d < 1024; d <<= 1) {
        int x = (t >= d) ? sd[t - d] : 0;
        __syncthreads();
        sd[t] += x;
        __syncthreads();
    }
    if (i < n) data[i] = sd[t] - val;
    if (t == 1023) bsum[blockIdx.x] = sd[1023];
}
__global__ void gscan2_kernel(const int* __restrict__ bsum, int* __restrict__ bpre, int nb) {
    int run = 0;
    for (int i = 0; i < nb; i++) { bpre[i] = run; run += bsum[i]; }
}
__global__ __launch_bounds__(1024) void gscan3_kernel(int* __restrict__ data,
                                                      const int* __restrict__ bpre, int n) {
    int i = blockIdx.x * 1024 + threadIdx.x;
    if (i < n) data[i] += bpre[blockIdx.x];
}

// ======== CSR phase 3: rank-scatter into bucket-grouped tmp ========
__global__ __launch_bounds__(256) void p3_scatter_kernel(const int* __restrict__ ei,
                                                         const int* __restrict__ cnt,
                                                         int* __restrict__ tmp) {
    __shared__ int hh[NB2];
    int t = threadIdx.x, blk = blockIdx.x;
    for (int b = t; b < NB2; b += 256) hh[b] = cnt[b * NBLK + blk];
    __syncthreads();
    for (int e = blk * 256 + t; e < NE; e += NBLK * 256) {
        int s = ei[e], tg = ei[NE + e];
        int pos = atomicAdd(&hh[tg >> 6], 1);
        tmp[pos] = ((tg & 63) << 16) | s;
    }
}

// ======== CSR phase 4: per-bucket fine CSR (off, indeg, srcs) ========
__global__ __launch_bounds__(256) void p4_fine_kernel(const int* __restrict__ tmp,
                                                      const int* __restrict__ cnt,
                                                      int* __restrict__ off,
                                                      int* __restrict__ indeg,
                                                      int* __restrict__ srcs) {
    __shared__ int c64[64], x64[64], cur[64];
    int b = blockIdx.x, t = threadIdx.x;
    int e0 = cnt[b * NBLK];
    int e1 = (b == NB2 - 1) ? NE : cnt[(b + 1) * NBLK];
    if (t < 64) c64[t] = 0;
    __syncthreads();
    for (int i = e0 + t; i < e1; i += 256) atomicAdd(&c64[(tmp[i] >> 16) & 63], 1);
    __syncthreads();
    if (t == 0) {
        int run = 0;
        for (int j = 0; j < 64; j++) { x64[j] = run; cur[j] = e0 + run; run += c64[j]; }
    }
    __syncthreads();
    if (t < 64) {
        int node = b * 64 + t;
        if (node <= NN) off[node] = e0 + x64[t];
        if (node < NN) indeg[node] = c64[t];
    }
    __syncthreads();
    for (int i = e0 + t; i < e1; i += 256) {
        int w = tmp[i];
        int pos = atomicAdd(&cur[(w >> 16) & 63], 1);
        srcs[pos] = w & 0xffff;
    }
}

// -------- weight prep: 13 matrices -> bf16 transposed [col][k] ------------
__global__ __launch_bounds__(256) void wprep_kernel(const float* __restrict__ Wq,
                                                    const float* __restrict__ Wk,
                                                    const float* __restrict__ Wv,
                                                    const float* __restrict__ Ws,
                                                    const float* __restrict__ Win,
                                                    unsigned short* __restrict__ Wt) {
    __shared__ unsigned short lds[128 * 130];
    int bid = blockIdx.x;
    const float* W;
    if (bid == 12) {
        W = Win;
    } else {
        int l = bid >> 2, m = bid & 3;
        W = (m == 0 ? Wq : m == 1 ? Wk : m == 2 ? Wv : Ws) + (size_t)l * DM * DM;
    }
    unsigned short* out = Wt + (size_t)bid * DM * DM;
    int t = threadIdx.x;
    for (int i = t; i < DM * DM; i += 256) {
        int kk = i >> 7, c = i & 127;
        lds[kk * 130 + c] = f2bf(W[i]);
    }
    __syncthreads();
    for (int o = t; o < DM * DM; o += 256) {
        int c = o >> 7, kk = o & 127;
        out[o] = lds[kk * 130 + c];
    }
}

// ---------------- x cast fp32 -> bf16 ----------------
__global__ __launch_bounds__(256) void xcast_kernel(const float* __restrict__ x,
                                                    unsigned short* __restrict__ xb) {
    int i = blockIdx.x * 256 + threadIdx.x;
    float4 xv = ((const float4*)x)[i];
    ushort4 o;
    o.x = f2bf(xv.x); o.y = f2bf(xv.y); o.z = f2bf(xv.z); o.w = f2bf(xv.w);
    ((ushort4*)xb)[i] = o;
}

// ------- input GEMM via MFMA (swapped operands) + embeddings
//         + FUSED layer-0 LayerNorm -> hn bf16 (cross-wave LDS reduce) -----
__global__ __launch_bounds__(256) void gemm_in_mfma(const unsigned short* __restrict__ xb,
                                                    const unsigned short* __restrict__ Wt,
                                                    const float* __restrict__ b,
                                                    const float* __restrict__ in_emb,
                                                    const float* __restrict__ out_emb,
                                                    const int* __restrict__ indeg,
                                                    const int* __restrict__ outdeg,
                                                    float* __restrict__ h,
                                                    const float* __restrict__ nsc,
                                                    const float* __restrict__ nbi,
                                                    unsigned short* __restrict__ hn) {
    __shared__ f32x2 pp[4][2][16];   // [wave][nt][lr] partial (sum, sumsq)
    int w = threadIdx.x >> 6;
    int l = threadIdx.x & 63;
    int lr = l & 15, lc = l >> 4;
    int colbase = (w & 1) * 64;
    int rhalf = w >> 1;

    short8 bfrag[4][4];
#pragma unroll
    for (int ct = 0; ct < 4; ct++) {
        const unsigned short* bp = Wt + (size_t)(colbase + ct * 16 + lr) * DM;
#pragma unroll
        for (int kk = 0; kk < 4; kk++)
            bfrag[ct][kk] = *(const short8*)(bp + kk * 32 + lc * 8);
    }

    for (int it = blockIdx.x; it < 782; it += gridDim.x) {
        int rg = it * 2 + rhalf;
        bool act = (rg < NRG);
        int n0 = rg * 32;
        float hval[2][16];
        float s2[2], q2[2];
        s2[0] = s2[1] = q2[0] = q2[1] = 0.f;

        if (act) {
            short8 afrag[2][4];
#pragma unroll
            for (int nt = 0; nt < 2; nt++) {
                int row = n0 + nt * 16 + lr;
                if (row >= NN) row = NN - 1;
                const unsigned short* ap = xb + (size_t)row * DM;
#pragma unroll
                for (int kk = 0; kk < 4; kk++)
                    afrag[nt][kk] = *(const short8*)(ap + kk * 32 + lc * 8);
            }
            f32x4 acc[4][2];
#pragma unroll
            for (int ct = 0; ct < 4; ct++)
#pragma unroll
                for (int nt = 0; nt < 2; nt++)
                    acc[ct][nt] = (f32x4){0.f, 0.f, 0.f, 0.f};
#pragma unroll
            for (int kk = 0; kk < 4; kk++)
#pragma unroll
                for (int ct = 0; ct < 4; ct++)
#pragma unroll
                    for (int nt = 0; nt < 2; nt++)
                        acc[ct][nt] = __builtin_amdgcn_mfma_f32_16x16x32_bf16(
                            bfrag[ct][kk], afrag[nt][kk], acc[ct][nt], 0, 0, 0);
#pragma unroll
            for (int nt = 0; nt < 2; nt++) {
                int node = n0 + nt * 16 + lr;
                int nodec = (node < NN) ? node : (NN - 1);
                int id = min(indeg[nodec], MAXDEG);
                int od = min(outdeg[nodec], MAXDEG);
                float s = 0.f, sq = 0.f;
#pragma unroll
                for (int ct = 0; ct < 4; ct++) {
                    int ch = colbase + ct * 16 + lc * 4;
                    float4 bb = *(const float4*)(b + ch);
                    float4 ie = *(const float4*)(in_emb + (size_t)id * DM + ch);
                    float4 oe = *(const float4*)(out_emb + (size_t)od * DM + ch);
                    float4 o;
                    o.x = acc[ct][nt][0] + bb.x + ie.x + oe.x;
                    o.y = acc[ct][nt][1] + bb.y + ie.y + oe.y;
                    o.z = acc[ct][nt][2] + bb.z + ie.z + oe.z;
                    o.w = acc[ct][nt][3] + bb.w + ie.w + oe.w;
                    hval[nt][ct * 4 + 0] = o.x;
                    hval[nt][ct * 4 + 1] = o.y;
                    hval[nt][ct * 4 + 2] = o.z;
                    hval[nt][ct * 4 + 3] = o.w;
                    s += o.x + o.y + o.z + o.w;
                    sq += o.x * o.x + o.y * o.y + o.z * o.z + o.w * o.w;
                    if (node < NN)
                        *(float4*)(h + (size_t)node * DM + ch) = o;
                }
                s += __shfl_xor(s, 16); s += __shfl_xor(s, 32);
                sq += __shfl_xor(sq, 16); sq += __shfl_xor(sq, 32);
                s2[nt] = s; q2[nt] = sq;
            }
        }
        __syncthreads();
        if (act && lc == 0) {
            pp[w][0][lr] = (f32x2){s2[0], q2[0]};
            pp[w][1][lr] = (f32x2){s2[1], q2[1]};
        }
        __syncthreads();
        if (act) {
#pragma unroll
            for (int nt = 0; nt < 2; nt++) {
                f32x2 po = pp[w ^ 1][nt][lr];
                float S = s2[nt] + po.x;
                float Q = q2[nt] + po.y;
                float mu = S * (1.f / 128.f);
                float var = Q * (1.f / 128.f) - mu * mu;
                float rstd = rsqrtf(var + 1e-5f);
                int node = n0 + nt * 16 + lr;
                if (node < NN) {
#pragma unroll
                    for (int ct = 0; ct < 4; ct++) {
                        int ch = colbase + ct * 16 + lc * 4;
                        float4 scv = *(const float4*)(nsc + ch);
                        float4 biv = *(const float4*)(nbi + ch);
                        ushort4 o;
                        o.x = f2bf((hval[nt][ct * 4 + 0] - mu) * rstd * scv.x + biv.x);
                        o.y = f2bf((hval[nt][ct * 4 + 1] - mu) * rstd * scv.y + biv.y);
                        o.z = f2bf((hval[nt][ct * 4 + 2] - mu) * rstd * scv.z + biv.z);
                        o.w = f2bf((hval[nt][ct * 4 + 3] - mu) * rstd * scv.w + biv.w);
                        *(ushort4*)(hn + (size_t)node * DM + ch) = o;
                    }
                }
            }
        }
    }
}

// ------- fused Q/K/V/skip GEMM via bf16 MFMA; LDS-staged A; swapped-operand
//         epilogue; kv8: per node, 8B group g = [k 4g..4g+3 | v 4g..4g+3] ---
__global__ __launch_bounds__(512) void gemm_qkvs_mfma(const unsigned short* __restrict__ hn,
                                                      const unsigned short* __restrict__ Wt,  // [512][128]
                                                      const float* __restrict__ bq, const float* __restrict__ bk,
                                                      const float* __restrict__ bv, const float* __restrict__ bs,
                                                      unsigned short* __restrict__ q,
                                                      unsigned char* __restrict__ kv8,
                                                      unsigned short* __restrict__ xrb) {
    __shared__ uint4 alds4[512];    // 32 rows x 128 ch bf16 = 8 KB
    unsigned short* alds = (unsigned short*)alds4;

    int w = threadIdx.x >> 6;       // 0..7
    int l = threadIdx.x & 63;
    int lr = l & 15, lc = l >> 4;
    int colbase = w * 64;
    int m = w >> 1;                 // wave-uniform: 0=q 1=k 2=v 3=skip
    int cmbase = (w & 1) * 64;
    int t = threadIdx.x;
    int ar = t >> 4;
    int ag = t & 15;
    int agx = ag ^ (ar & 7);

    const float* bptr = (m == 0 ? bq : m == 1 ? bk : m == 2 ? bv : bs);
    short8 bfrag[4][4];
    float biasv[4][4];
#pragma unroll
    for (int ct = 0; ct < 4; ct++) {
        int col = colbase + ct * 16 + lr;
        const unsigned short* bp = Wt + (size_t)col * DM;
#pragma unroll
        for (int kk = 0; kk < 4; kk++)
            bfrag[ct][kk] = *(const short8*)(bp + kk * 32 + lc * 8);
#pragma unroll
        for (int j = 0; j < 4; j++)
            biasv[ct][j] = bptr[cmbase + ct * 16 + lc * 4 + j];
    }

    for (int rg = blockIdx.x; rg < NRG; rg += gridDim.x) {
        int n0 = rg * 32;
        int grow = n0 + ar;
        if (grow >= NN) grow = NN - 1;
        uint4 av = *(const uint4*)(hn + (size_t)grow * DM + ag * 8);
        __syncthreads();
        alds4[ar * 16 + agx] = av;
        __syncthreads();

        short8 afrag[2][4];
#pragma unroll
        for (int nt = 0; nt < 2; nt++)
#pragma unroll
            for (int kk = 0; kk < 4; kk++) {
                int g = kk * 4 + lc;
                int gx = g ^ (lr & 7);
                afrag[nt][kk] = *(const short8*)(alds + (nt * 16 + lr) * 128 + gx * 8);
            }

        f32x4 acc[4][2];
#pragma unroll
        for (int ct = 0; ct < 4; ct++)
#pragma unroll
            for (int nt = 0; nt < 2; nt++)
                acc[ct][nt] = (f32x4){0.f, 0.f, 0.f, 0.f};
#pragma unroll
        for (int kk = 0; kk < 4; kk++)
#pragma unroll
            for (int ct = 0; ct < 4; ct++)
#pragma unroll
                for (int nt = 0; nt < 2; nt++)
                    acc[ct][nt] = __builtin_amdgcn_mfma_f32_16x16x32_bf16(
                        bfrag[ct][kk], afrag[nt][kk], acc[ct][nt], 0, 0, 0);

        if (m == 0 || m == 3) {
            unsigned short* dst = (m == 0) ? q : xrb;
#pragma unroll
            for (int nt = 0; nt < 2; nt++) {
                int node = n0 + nt * 16 + lr;
                if (node < NN) {
#pragma unroll
                    for (int ct = 0; ct < 4; ct++) {
                        int ch = cmbase + ct * 16 + lc * 4;
                        ushort4 st;
                        st.x = f2bf(acc[ct][nt][0] + biasv[ct][0]);
                        st.y = f2bf(acc[ct][nt][1] + biasv[ct][1]);
                        st.z = f2bf(acc[ct][nt][2] + biasv[ct][2]);
                        st.w = f2bf(acc[ct][nt][3] + biasv[ct][3]);
                        *(ushort4*)(dst + (size_t)node * DM + ch) = st;
                    }
                }
            }
        } else {
            unsigned char* base = kv8 + ((m == 1) ? 0 : 4);
#pragma unroll
            for (int nt = 0; nt < 2; nt++) {
                int node = n0 + nt * 16 + lr;
                if (node < NN) {
#pragma unroll
                    for (int ct = 0; ct < 4; ct++) {
                        int ch = cmbase + ct * 16 + lc * 4;
                        int wd = __builtin_amdgcn_cvt_pk_fp8_f32(
                            acc[ct][nt][0] + biasv[ct][0],
                            acc[ct][nt][1] + biasv[ct][1], 0, false);
                        wd = __builtin_amdgcn_cvt_pk_fp8_f32(
                            acc[ct][nt][2] + biasv[ct][2],
                            acc[ct][nt][3] + biasv[ct][3], wd, true);
                        *(unsigned int*)(base + (size_t)node * 256 + (ch >> 2) * 8) =
                            (unsigned int)wd;
                    }
                }
            }
        }
    }
}

// ---- fused attention (r14 structure; exp2-based softmax): one wave per
//      node; 4 ch/lane over 32 lanes; chunk-16 unchecked + masked tail;
//      beta gate + h update + fused next-layer LN or fused final LN --------
__global__ __launch_bounds__(256) void attn_fused_kernel(const int* __restrict__ off,
                                                         const int* __restrict__ srcs,
                                                         const unsigned short* __restrict__ q,
                                                         const unsigned char* __restrict__ kv8,
                                                         const unsigned short* __restrict__ xrb,
                                                         const float* __restrict__ Wb,
                                                         float* __restrict__ h,
                                                         const float* __restrict__ nsc,
                                                         const float* __restrict__ nbi,
                                                         unsigned short* __restrict__ hn_out,
                                                         const float* __restrict__ fsc,
                                                         const float* __restrict__ fbi,
                                                         float* __restrict__ fout) {
    int wv = threadIdx.x >> 6;    // 4 nodes per block
    int L = threadIdx.x & 63;
    int half = L >> 5, L5 = L & 31;
    int n = blockIdx.x * 4 + wv;
    int o0 = off[n], o1 = off[n + 1];
    int c4 = L5 * 4;
    // softmax base-2: fold 1/sqrt(8) * log2(e) into the q scale
    const float isq = 0.35355339059f * 1.44269504089f;

    ushort4 qu = *(const ushort4*)(q + (size_t)n * DM + c4);
    float q0 = bf2f(qu.x) * isq, q1 = bf2f(qu.y) * isq,
          q2 = bf2f(qu.z) * isq, q3 = bf2f(qu.w) * isq;

    float den = 0.f, a0 = 0.f, a1 = 0.f, a2 = 0.f, a3 = 0.f;
    int p = o0;
    // ---- full chunks: no bounds checks anywhere ----
    for (; p + 16 <= o1; p += 16) {
        int sj[8];
#pragma unroll
        for (int j = 0; j < 8; j++) sj[j] = srcs[p + 2 * j + half];
        uint2 uu[8];
#pragma unroll
        for (int j = 0; j < 8; j++)
            uu[j] = *(const uint2*)(kv8 + (size_t)sj[j] * 256 + L5 * 8);
#pragma unroll
        for (int j = 0; j < 8; j++) {
            f32x2 k01 = __builtin_amdgcn_cvt_pk_f32_fp8(uu[j].x, false);
            f32x2 k23 = __builtin_amdgcn_cvt_pk_f32_fp8(uu[j].x, true);
            f32x2 v01 = __builtin_amdgcn_cvt_pk_f32_fp8(uu[j].y, false);
            f32x2 v23 = __builtin_amdgcn_cvt_pk_f32_fp8(uu[j].y, true);
            float d = q0 * k01.x + q1 * k01.y + q2 * k23.x + q3 * k23.y;
            d += __shfl_xor(d, 1);  // 8-channel head dot (2 lanes/head)
            float e2 = exp2f(d);
            den += e2;
            a0 += e2 * v01.x;
            a1 += e2 * v01.y;
            a2 += e2 * v23.x;
            a3 += e2 * v23.y;
        }
    }
    // ---- masked tail chunk (0..15 remaining edges) ----
    if (p < o1) {
        int sj[8];
#pragma unroll
        for (int j = 0; j < 8; j++) {
            int e = p + 2 * j + half;
            sj[j] = (e < o1) ? srcs[e] : 0;
        }
        uint2 uu[8];
#pragma unroll
        for (int j = 0; j < 8; j++)
            uu[j] = *(const uint2*)(kv8 + (size_t)sj[j] * 256 + L5 * 8);
#pragma unroll
        for (int j = 0; j < 8; j++) {
            int e = p + 2 * j + half;
            f32x2 k01 = __builtin_amdgcn_cvt_pk_f32_fp8(uu[j].x, false);
            f32x2 k23 = __builtin_amdgcn_cvt_pk_f32_fp8(uu[j].x, true);
            f32x2 v01 = __builtin_amdgcn_cvt_pk_f32_fp8(uu[j].y, false);
            f32x2 v23 = __builtin_amdgcn_cvt_pk_f32_fp8(uu[j].y, true);
            float d = q0 * k01.x + q1 * k01.y + q2 * k23.x + q3 * k23.y;
            d += __shfl_xor(d, 1);
            float e2 = (e < o1) ? exp2f(d) : 0.f;
            den += e2;
            a0 += e2 * v01.x;
            a1 += e2 * v01.y;
            a2 += e2 * v23.x;
            a3 += e2 * v23.y;
        }
    }
    // combine the two half-wave edge partitions (same channels)
    den += __shfl_xor(den, 32);
    a0 += __shfl_xor(a0, 32);
    a1 += __shfl_xor(a1, 32);
    a2 += __shfl_xor(a2, 32);
    a3 += __shfl_xor(a3, 32);

    float inv = (den > 0.f) ? 1.f / den : 0.f;
    float o0v = a0 * inv, o1v = a1 * inv, o2v = a2 * inv, o3v = a3 * inv;

    ushort4 xu = *(const ushort4*)(xrb + (size_t)n * DM + c4);
    float x0 = bf2f(xu.x), x1 = bf2f(xu.y), x2 = bf2f(xu.z), x3 = bf2f(xu.w);
    float c = o0v * Wb[c4] + o1v * Wb[c4 + 1] + o2v * Wb[c4 + 2] + o3v * Wb[c4 + 3]
            + x0 * Wb[DM + c4] + x1 * Wb[DM + c4 + 1]
            + x2 * Wb[DM + c4 + 2] + x3 * Wb[DM + c4 + 3]
            + (o0v - x0) * Wb[2 * DM + c4] + (o1v - x1) * Wb[2 * DM + c4 + 1]
            + (o2v - x2) * Wb[2 * DM + c4 + 2] + (o3v - x3) * Wb[2 * DM + c4 + 3];
    if (half) c = 0.f;   // avoid double-count: channels duplicated across halves
#pragma unroll
    for (int d2 = 32; d2; d2 >>= 1) c += __shfl_xor(c, d2);
    float beta = 1.f / (1.f + __expf(-c));

    size_t idx = (size_t)n * DM + c4;
    float4 hv = *(const float4*)(h + idx);
    hv.x += beta * x0 + (1.f - beta) * o0v;
    hv.y += beta * x1 + (1.f - beta) * o1v;
    hv.z += beta * x2 + (1.f - beta) * o2v;
    hv.w += beta * x3 + (1.f - beta) * o3v;

    if (fout) {
        // final LayerNorm fused -> fp32 d_out
        float s = hv.x + hv.y + hv.z + hv.w;
#pragma unroll
        for (int d2 = 16; d2; d2 >>= 1) s += __shfl_xor(s, d2);
        float mu = s * (1.f / 128.f);
        float d0 = hv.x - mu, d1 = hv.y - mu, d2_ = hv.z - mu, d3 = hv.w - mu;
        float vs = d0 * d0 + d1 * d1 + d2_ * d2_ + d3 * d3;
#pragma unroll
        for (int d2 = 16; d2; d2 >>= 1) vs += __shfl_xor(vs, d2);
        float rstd = rsqrtf(vs * (1.f / 128.f) + 1e-5f);
        if (half == 0) {
            float4 scv = *(const float4*)(fsc + c4);
            float4 biv = *(const float4*)(fbi + c4);
            float4 o;
            o.x = d0 * rstd * scv.x + biv.x;
            o.y = d1 * rstd * scv.y + biv.y;
            o.z = d2_ * rstd * scv.z + biv.z;
            o.w = d3 * rstd * scv.w + biv.w;
            *(float4*)(fout + idx) = o;
        }
    } else {
        if (half == 0) *(float4*)(h + idx) = hv;
        // next-layer LayerNorm fused -> hn bf16
        float s = hv.x + hv.y + hv.z + hv.w;
#pragma unroll
        for (int d2 = 16; d2; d2 >>= 1) s += __shfl_xor(s, d2);
        float mu = s * (1.f / 128.f);
        float d0 = hv.x - mu, d1 = hv.y - mu, d2_ = hv.z - mu, d3 = hv.w - mu;
        float vs = d0 * d0 + d1 * d1 + d2_ * d2_ + d3 * d3;
#pragma unroll
        for (int d2 = 16; d2; d2 >>= 1) vs += __shfl_xor(vs, d2);
        float rstd = rsqrtf(vs * (1.f / 128.f) + 1e-5f);
        if (half == 0) {
            float4 scv = *(const float4*)(nsc + c4);
            float4 biv = *(const float4*)(nbi + c4);
            ushort4 o;
            o.x = f2bf(d0 * rstd * scv.x + biv.x);
            o.y = f2bf(d1 * rstd * scv.y + biv.y);
            o.z = f2bf(d2_ * rstd * scv.z + biv.z);
            o.w = f2bf(d3 * rstd * scv.w + biv.w);
            *(ushort4*)(hn_out + idx) = o;
        }
    }
}

static inline char* alignup(char* p) {
    return (char*)(((uintptr_t)p + 255) & ~(uintptr_t)255);
}

extern "C" void kernel_launch(void* const* d_in, const int* in_sizes, int n_in,
                              void* d_out, int out_size, void* d_ws, size_t ws_size,
                              hipStream_t stream) {
    const float* x       = (const float*)d_in[0];
    const int*   ei      = (const int*)d_in[1];
    const float* W_in    = (const float*)d_in[2];
    const float* b_in    = (const float*)d_in[3];
    const float* in_emb  = (const float*)d_in[4];
    const float* out_emb = (const float*)d_in[5];
    const float* ln_sc   = (const float*)d_in[6];
    const float* ln_bi   = (const float*)d_in[7];
    const float* Wq      = (const float*)d_in[8];
    const float* bq      = (const float*)d_in[9];
    const float* Wk      = (const float*)d_in[10];
    const float* bk      = (const float*)d_in[11];
    const float* Wv      = (const float*)d_in[12];
    const float* bv      = (const float*)d_in[13];
    const float* Wsk     = (const float*)d_in[14];
    const float* bsk     = (const float*)d_in[15];
    const float* Wbeta   = (const float*)d_in[16];
    const float* fn_sc   = (const float*)d_in[17];
    const float* fn_bi   = (const float*)d_in[18];

    char* w = (char*)d_ws;
    int* indeg  = (int*)w; w = alignup(w + (size_t)NN * 4);
    int* outdeg = (int*)w; w = alignup(w + (size_t)NN * 4);
    int* off    = (int*)w; w = alignup(w + (size_t)(NN + 1) * 4);
    int* srcs   = (int*)w; w = alignup(w + (size_t)NE * 4);
    int* tmp    = (int*)w; w = alignup(w + (size_t)NE * 4);
    int* cnt    = (int*)w; w = alignup(w + (size_t)CNTN * 4);
    int* bsum   = (int*)w; w = alignup(w + (size_t)SC1 * 4);
    int* bpre   = (int*)w; w = alignup(w + (size_t)SC1 * 4);
    unsigned int* hpart = (unsigned int*)w; w = alignup(w + (size_t)RNG * REP * 8192 * 4);
    float* h    = (float*)w; w = alignup(w + (size_t)NN * DM * 4);
    unsigned short* hn  = (unsigned short*)w; w = alignup(w + (size_t)NN * DM * 2);
    unsigned short* q   = (unsigned short*)w; w = alignup(w + (size_t)NN * DM * 2);
    unsigned short* xrb = (unsigned short*)w; w = alignup(w + (size_t)NN * DM * 2);
    unsigned char*  kv8 = (unsigned char*)w;  w = alignup(w + (size_t)NN * 256);
    unsigned short* xb  = (unsigned short*)w; w = alignup(w + (size_t)NN * DM * 2);
    unsigned short* Wt  = (unsigned short*)w; w = alignup(w + (size_t)13 * DM * DM * 2);

    // ---- CSR build (no global atomics) ----
    hist_out_kernel<<<dim3(RNG, REP), 1024, 0, stream>>>(ei, hpart);
    hist_reduce_kernel<<<98, 256, 0, stream>>>(hpart, outdeg);
    p1_count_kernel<<<NBLK, 256, 0, stream>>>(ei, cnt);
    gscan1_kernel<<<SC1, 1024, 0, stream>>>(cnt, bsum, CNTN);
    gscan2_kernel<<<1, 1, 0, stream>>>(bsum, bpre, SC1);
    gscan3_kernel<<<SC1, 1024, 0, stream>>>(cnt, bpre, CNTN);
    p3_scatter_kernel<<<NBLK, 256, 0, stream>>>(ei, cnt, tmp);
    p4_fine_kernel<<<NB2, 256, 0, stream>>>(tmp, cnt, off, indeg, srcs);

    wprep_kernel<<<13, 256, 0, stream>>>(Wq, Wk, Wv, Wsk, W_in, Wt);
    xcast_kernel<<<NN * DM / 4 / 256, 256, 0, stream>>>(x, xb);

    gemm_in_mfma<<<391, 256, 0, stream>>>(xb, Wt + (size_t)12 * DM * DM, b_in,
                                          in_emb, out_emb, indeg, outdeg, h,
                                          ln_sc, ln_bi, hn);
    for (int l = 0; l < NL; l++) {
        gemm_qkvs_mfma<<<391, 512, 0, stream>>>(hn,
            Wt + (size_t)l * 4 * DM * DM,
            bq + l * DM, bk + l * DM, bv + l * DM, bsk + l * DM,
            q, kv8, xrb);
        bool last = (l == NL - 1);
        attn_fused_kernel<<<NN / 4, 256, 0, stream>>>(off, srcs, q, kv8, xrb,
            Wbeta + (size_t)l * 3 * DM, h,
            last ? (const float*)nullptr : ln_sc + (l + 1) * DM,
            last ? (const float*)nullptr : ln_bi + (l + 1) * DM,
            last ? (unsigned short*)nullptr : hn,
            last ? fn_sc : (const float*)nullptr,
            last ? fn_bi : (const float*)nullptr,
            last ? (float*)d_out : (float*)nullptr);
    }
}

// Round 17
// 332.101 us; speedup vs baseline: 1.0518x; 1.0163x over previous
//
#include <hip/hip_runtime.h>
#include <math.h>
#include <stdint.h>

#define NN 50000
#define DM 128
#define NH 16
#define HC 8
#define NL 3
#define NE 800000
#define MAXDEG 512
#define NRG 1563   // ceil(50000/32) row groups

// CSR-build geometry
#define NB2 782            // coarse buckets of 64 target nodes (782*64=50048)
#define NBLK 256           // blocks in count/scatter phases
#define CNTN (NB2 * NBLK)  // count-matrix entries = 200192
#define SC1 196            // ceil(CNTN/1024)
#define RNG 4              // node ranges for outdeg histogram (16384 nodes each)
#define REP 16             // replicas per range

typedef __attribute__((ext_vector_type(8))) short short8;
typedef __attribute__((ext_vector_type(4))) float f32x4;
typedef __attribute__((ext_vector_type(2))) float f32x2;

static __device__ __forceinline__ unsigned short f2bf(float x) {
    union { float f; unsigned int u; } v; v.f = x;
    unsigned int r = (v.u + 0x7fffu + ((v.u >> 16) & 1u)) >> 16;
    return (unsigned short)r;
}
static __device__ __forceinline__ float bf2f(unsigned short b) {
    union { unsigned int u; float f; } v; v.u = ((unsigned int)b) << 16;
    return v.f;
}

// ======== outdeg histogram: LDS packed-u16, no global atomics ========
__global__ __launch_bounds__(1024) void hist_out_kernel(const int* __restrict__ ei,
                                                        unsigned int* __restrict__ part) {
    __shared__ unsigned int hp[8192];
    int rg = blockIdx.x;
    int rp = blockIdx.y;
    int t = threadIdx.x;
    for (int i = t; i < 8192; i += 1024) hp[i] = 0;
    __syncthreads();
    int lo = rg << 14;
    for (int e = rp * 1024 + t; e < NE; e += REP * 1024) {
        int s = ei[e] - lo;
        if ((unsigned)s < 16384u)
            atomicAdd(&hp[s >> 1], (s & 1) ? 0x10000u : 1u);
    }
    __syncthreads();
    unsigned int* pp = part + (size_t)(rg * REP + rp) * 8192;
    for (int i = t; i < 8192; i += 1024) pp[i] = hp[i];
}
__global__ __launch_bounds__(256) void hist_reduce_kernel(const unsigned int* __restrict__ part,
                                                          int* __restrict__ outdeg) {
    int wd = blockIdx.x * 256 + threadIdx.x;
    if (wd >= 25000) return;
    int rg = wd >> 13, lw = wd & 8191;
    unsigned int sum = 0;
#pragma unroll
    for (int r = 0; r < REP; r++)
        sum += part[(size_t)(rg * REP + r) * 8192 + lw];
    outdeg[2 * wd] = sum & 0xffff;
    if (2 * wd + 1 < NN) outdeg[2 * wd + 1] = sum >> 16;
}

// ======== CSR build phase 1: per-(block,bucket) counts ========
__global__ __launch_bounds__(256) void p1_count_kernel(const int* __restrict__ ei,
                                                       int* __restrict__ cnt) {
    __shared__ int hh[NB2];
    int t = threadIdx.x, blk = blockIdx.x;
    for (int b = t; b < NB2; b += 256) hh[b] = 0;
    __syncthreads();
    for (int e = blk * 256 + t; e < NE; e += NBLK * 256)
        atomicAdd(&hh[ei[NE + e] >> 6], 1);
    __syncthreads();
    for (int b = t; b < NB2; b += 256) cnt[b * NBLK + blk] = hh[b];
}

// ======== generic 3-kernel exclusive scan ========
__global__ __launch_bounds__(1024) void gscan1_kernel(int* __restrict__ data,
                                                      int* __restrict__ bsum, int n) {
    __shared__ int sd[1024];
    int t = threadIdx.x;
    int i = blockIdx.x * 1024 + t;
    int val = (i < n) ? data[i] : 0;
    sd[t] = val;
    __syncthreads();
    for (int d = 1; d < 1024; d <<= 1) {
        int x = (t >= d) ? sd[t - d] : 0;
        __syncthreads();
        sd[t] += x;
        __syncthreads();
    }
    if (i < n) data[i] = sd[t] - val;
    if (t == 1023) bsum[blockIdx.x] = sd[1023];
}
__global__ void gscan2_kernel(const int* __restrict__ bsum, int* __restrict__ bpre, int nb) {
    int run = 0;
    for (int i = 0; i < nb; i++) { bpre[i] = run; run += bsum[i]; }
}
__global__ __launch_bounds__(1024) void gscan3_kernel(int* __restrict__ data,
                                                      const int* __restrict__ bpre, int n) {
    int i = blockIdx.x * 1024 + threadIdx.x;
    if (i < n) data[i] += bpre[blockIdx.x];
}

// ======== CSR phase 3: rank-scatter into bucket-grouped tmp ========
__global__ __launch_bounds__(256) void p3_scatter_kernel(const int* __restrict__ ei,
                                                         const int* __restrict__ cnt,
                                                         int* __restrict__ tmp) {
    __shared__ int hh[NB2];
    int t = threadIdx.x, blk = blockIdx.x;
    for (int b = t; b < NB2; b += 256) hh[b] = cnt[b * NBLK + blk];
    __syncthreads();
    for (int e = blk * 256 + t; e < NE; e += NBLK * 256) {
        int s = ei[e], tg = ei[NE + e];
        int pos = atomicAdd(&hh[tg >> 6], 1);
        tmp[pos] = ((tg & 63) << 16) | s;
    }
}

// ======== CSR phase 4: per-bucket fine CSR (off, indeg, srcs) ========
__global__ __launch_bounds__(256) void p4_fine_kernel(const int* __restrict__ tmp,
                                                      const int* __restrict__ cnt,
                                                      int* __restrict__ off,
                                                      int* __restrict__ indeg,
                                                      int* __restrict__ srcs) {
    __shared__ int c64[64], x64[64], cur[64];
    int b = blockIdx.x, t = threadIdx.x;
    int e0 = cnt[b * NBLK];
    int e1 = (b == NB2 - 1) ? NE : cnt[(b + 1) * NBLK];
    if (t < 64) c64[t] = 0;
    __syncthreads();
    for (int i = e0 + t; i < e1; i += 256) atomicAdd(&c64[(tmp[i] >> 16) & 63], 1);
    __syncthreads();
    if (t == 0) {
        int run = 0;
        for (int j = 0; j < 64; j++) { x64[j] = run; cur[j] = e0 + run; run += c64[j]; }
    }
    __syncthreads();
    if (t < 64) {
        int node = b * 64 + t;
        if (node <= NN) off[node] = e0 + x64[t];
        if (node < NN) indeg[node] = c64[t];
    }
    __syncthreads();
    for (int i = e0 + t; i < e1; i += 256) {
        int w = tmp[i];
        int pos = atomicAdd(&cur[(w >> 16) & 63], 1);
        srcs[pos] = w & 0xffff;
    }
}

// -------- weight prep: 13 matrices -> bf16 transposed [col][k] ------------
__global__ __launch_bounds__(256) void wprep_kernel(const float* __restrict__ Wq,
                                                    const float* __restrict__ Wk,
                                                    const float* __restrict__ Wv,
                                                    const float* __restrict__ Ws,
                                                    const float* __restrict__ Win,
                                                    unsigned short* __restrict__ Wt) {
    __shared__ unsigned short lds[128 * 130];
    int bid = blockIdx.x;
    const float* W;
    if (bid == 12) {
        W = Win;
    } else {
        int l = bid >> 2, m = bid & 3;
        W = (m == 0 ? Wq : m == 1 ? Wk : m == 2 ? Wv : Ws) + (size_t)l * DM * DM;
    }
    unsigned short* out = Wt + (size_t)bid * DM * DM;
    int t = threadIdx.x;
    for (int i = t; i < DM * DM; i += 256) {
        int kk = i >> 7, c = i & 127;
        lds[kk * 130 + c] = f2bf(W[i]);
    }
    __syncthreads();
    for (int o = t; o < DM * DM; o += 256) {
        int c = o >> 7, kk = o & 127;
        out[o] = lds[kk * 130 + c];
    }
}

// ---------------- x cast fp32 -> bf16 ----------------
__global__ __launch_bounds__(256) void xcast_kernel(const float* __restrict__ x,
                                                    unsigned short* __restrict__ xb) {
    int i = blockIdx.x * 256 + threadIdx.x;
    float4 xv = ((const float4*)x)[i];
    ushort4 o;
    o.x = f2bf(xv.x); o.y = f2bf(xv.y); o.z = f2bf(xv.z); o.w = f2bf(xv.w);
    ((ushort4*)xb)[i] = o;
}

// ------- input GEMM via MFMA (swapped operands) + embeddings
//         + FUSED layer-0 LayerNorm -> hn bf16 (cross-wave LDS reduce) -----
__global__ __launch_bounds__(256) void gemm_in_mfma(const unsigned short* __restrict__ xb,
                                                    const unsigned short* __restrict__ Wt,
                                                    const float* __restrict__ b,
                                                    const float* __restrict__ in_emb,
                                                    const float* __restrict__ out_emb,
                                                    const int* __restrict__ indeg,
                                                    const int* __restrict__ outdeg,
                                                    float* __restrict__ h,
                                                    const float* __restrict__ nsc,
                                                    const float* __restrict__ nbi,
                                                    unsigned short* __restrict__ hn) {
    __shared__ f32x2 pp[4][2][16];   // [wave][nt][lr] partial (sum, sumsq)
    int w = threadIdx.x >> 6;
    int l = threadIdx.x & 63;
    int lr = l & 15, lc = l >> 4;
    int colbase = (w & 1) * 64;
    int rhalf = w >> 1;

    short8 bfrag[4][4];
#pragma unroll
    for (int ct = 0; ct < 4; ct++) {
        const unsigned short* bp = Wt + (size_t)(colbase + ct * 16 + lr) * DM;
#pragma unroll
        for (int kk = 0; kk < 4; kk++)
            bfrag[ct][kk] = *(const short8*)(bp + kk * 32 + lc * 8);
    }

    for (int it = blockIdx.x; it < 782; it += gridDim.x) {
        int rg = it * 2 + rhalf;
        bool act = (rg < NRG);
        int n0 = rg * 32;
        float hval[2][16];
        float s2[2], q2[2];
        s2[0] = s2[1] = q2[0] = q2[1] = 0.f;

        if (act) {
            short8 afrag[2][4];
#pragma unroll
            for (int nt = 0; nt < 2; nt++) {
                int row = n0 + nt * 16 + lr;
                if (row >= NN) row = NN - 1;
                const unsigned short* ap = xb + (size_t)row * DM;
#pragma unroll
                for (int kk = 0; kk < 4; kk++)
                    afrag[nt][kk] = *(const short8*)(ap + kk * 32 + lc * 8);
            }
            f32x4 acc[4][2];
#pragma unroll
            for (int ct = 0; ct < 4; ct++)
#pragma unroll
                for (int nt = 0; nt < 2; nt++)
                    acc[ct][nt] = (f32x4){0.f, 0.f, 0.f, 0.f};
#pragma unroll
            for (int kk = 0; kk < 4; kk++)
#pragma unroll
                for (int ct = 0; ct < 4; ct++)
#pragma unroll
                    for (int nt = 0; nt < 2; nt++)
                        acc[ct][nt] = __builtin_amdgcn_mfma_f32_16x16x32_bf16(
                            bfrag[ct][kk], afrag[nt][kk], acc[ct][nt], 0, 0, 0);
#pragma unroll
            for (int nt = 0; nt < 2; nt++) {
                int node = n0 + nt * 16 + lr;
                int nodec = (node < NN) ? node : (NN - 1);
                int id = min(indeg[nodec], MAXDEG);
                int od = min(outdeg[nodec], MAXDEG);
                float s = 0.f, sq = 0.f;
#pragma unroll
                for (int ct = 0; ct < 4; ct++) {
                    int ch = colbase + ct * 16 + lc * 4;
                    float4 bb = *(const float4*)(b + ch);
                    float4 ie = *(const float4*)(in_emb + (size_t)id * DM + ch);
                    float4 oe = *(const float4*)(out_emb + (size_t)od * DM + ch);
                    float4 o;
                    o.x = acc[ct][nt][0] + bb.x + ie.x + oe.x;
                    o.y = acc[ct][nt][1] + bb.y + ie.y + oe.y;
                    o.z = acc[ct][nt][2] + bb.z + ie.z + oe.z;
                    o.w = acc[ct][nt][3] + bb.w + ie.w + oe.w;
                    hval[nt][ct * 4 + 0] = o.x;
                    hval[nt][ct * 4 + 1] = o.y;
                    hval[nt][ct * 4 + 2] = o.z;
                    hval[nt][ct * 4 + 3] = o.w;
                    s += o.x + o.y + o.z + o.w;
                    sq += o.x * o.x + o.y * o.y + o.z * o.z + o.w * o.w;
                    if (node < NN)
                        *(float4*)(h + (size_t)node * DM + ch) = o;
                }
                s += __shfl_xor(s, 16); s += __shfl_xor(s, 32);
                sq += __shfl_xor(sq, 16); sq += __shfl_xor(sq, 32);
                s2[nt] = s; q2[nt] = sq;
            }
        }
        __syncthreads();
        if (act && lc == 0) {
            pp[w][0][lr] = (f32x2){s2[0], q2[0]};
            pp[w][1][lr] = (f32x2){s2[1], q2[1]};
        }
        __syncthreads();
        if (act) {
#pragma unroll
            for (int nt = 0; nt < 2; nt++) {
                f32x2 po = pp[w ^ 1][nt][lr];
                float S = s2[nt] + po.x;
                float Q = q2[nt] + po.y;
                float mu = S * (1.f / 128.f);
                float var = Q * (1.f / 128.f) - mu * mu;
                float rstd = rsqrtf(var + 1e-5f);
                int node = n0 + nt * 16 + lr;
                if (node < NN) {
#pragma unroll
                    for (int ct = 0; ct < 4; ct++) {
                        int ch = colbase + ct * 16 + lc * 4;
                        float4 scv = *(const float4*)(nsc + ch);
                        float4 biv = *(const float4*)(nbi + ch);
                        ushort4 o;
                        o.x = f2bf((hval[nt][ct * 4 + 0] - mu) * rstd * scv.x + biv.x);
                        o.y = f2bf((hval[nt][ct * 4 + 1] - mu) * rstd * scv.y + biv.y);
                        o.z = f2bf((hval[nt][ct * 4 + 2] - mu) * rstd * scv.z + biv.z);
                        o.w = f2bf((hval[nt][ct * 4 + 3] - mu) * rstd * scv.w + biv.w);
                        *(ushort4*)(hn + (size_t)node * DM + ch) = o;
                    }
                }
            }
        }
    }
}

// ------- fused Q/K/V/skip GEMM via bf16 MFMA; LDS-staged A; swapped-operand
//         epilogue; kv8: per node, 8B group g = [k 4g..4g+3 | v 4g..4g+3] ---
__global__ __launch_bounds__(512) void gemm_qkvs_mfma(const unsigned short* __restrict__ hn,
                                                      const unsigned short* __restrict__ Wt,  // [512][128]
                                                      const float* __restrict__ bq, const float* __restrict__ bk,
                                                      const float* __restrict__ bv, const float* __restrict__ bs,
                                                      unsigned short* __restrict__ q,
                                                      unsigned char* __restrict__ kv8,
                                                      unsigned short* __restrict__ xrb) {
    __shared__ uint4 alds4[512];    // 32 rows x 128 ch bf16 = 8 KB
    unsigned short* alds = (unsigned short*)alds4;

    int w = threadIdx.x >> 6;       // 0..7
    int l = threadIdx.x & 63;
    int lr = l & 15, lc = l >> 4;
    int colbase = w * 64;
    int m = w >> 1;                 // wave-uniform: 0=q 1=k 2=v 3=skip
    int cmbase = (w & 1) * 64;
    int t = threadIdx.x;
    int ar = t >> 4;
    int ag = t & 15;
    int agx = ag ^ (ar & 7);

    const float* bptr = (m == 0 ? bq : m == 1 ? bk : m == 2 ? bv : bs);
    short8 bfrag[4][4];
    float biasv[4][4];
#pragma unroll
    for (int ct = 0; ct < 4; ct++) {
        int col = colbase + ct * 16 + lr;
        const unsigned short* bp = Wt + (size_t)col * DM;
#pragma unroll
        for (int kk = 0; kk < 4; kk++)
            bfrag[ct][kk] = *(const short8*)(bp + kk * 32 + lc * 8);
#pragma unroll
        for (int j = 0; j < 4; j++)
            biasv[ct][j] = bptr[cmbase + ct * 16 + lc * 4 + j];
    }

    for (int rg = blockIdx.x; rg < NRG; rg += gridDim.x) {
        int n0 = rg * 32;
        int grow = n0 + ar;
        if (grow >= NN) grow = NN - 1;
        uint4 av = *(const uint4*)(hn + (size_t)grow * DM + ag * 8);
        __syncthreads();
        alds4[ar * 16 + agx] = av;
        __syncthreads();

        short8 afrag[2][4];
#pragma unroll
        for (int nt = 0; nt < 2; nt++)
#pragma unroll
            for (int kk = 0; kk < 4; kk++) {
                int g = kk * 4 + lc;
                int gx = g ^ (lr & 7);
                afrag[nt][kk] = *(const short8*)(alds + (nt * 16 + lr) * 128 + gx * 8);
            }

        f32x4 acc[4][2];
#pragma unroll
        for (int ct = 0; ct < 4; ct++)
#pragma unroll
            for (int nt = 0; nt < 2; nt++)
                acc[ct][nt] = (f32x4){0.f, 0.f, 0.f, 0.f};
#pragma unroll
        for (int kk = 0; kk < 4; kk++)
#pragma unroll
            for (int ct = 0; ct < 4; ct++)
#pragma unroll
                for (int nt = 0; nt < 2; nt++)
                    acc[ct][nt] = __builtin_amdgcn_mfma_f32_16x16x32_bf16(
                        bfrag[ct][kk], afrag[nt][kk], acc[ct][nt], 0, 0, 0);

        if (m == 0 || m == 3) {
            unsigned short* dst = (m == 0) ? q : xrb;
#pragma unroll
            for (int nt = 0; nt < 2; nt++) {
                int node = n0 + nt * 16 + lr;
                if (node < NN) {
#pragma unroll
                    for (int ct = 0; ct < 4; ct++) {
                        int ch = cmbase + ct * 16 + lc * 4;
                        ushort4 st;
                        st.x = f2bf(acc[ct][nt][0] + biasv[ct][0]);
                        st.y = f2bf(acc[ct][nt][1] + biasv[ct][1]);
                        st.z = f2bf(acc[ct][nt][2] + biasv[ct][2]);
                        st.w = f2bf(acc[ct][nt][3] + biasv[ct][3]);
                        *(ushort4*)(dst + (size_t)node * DM + ch) = st;
                    }
                }
            }
        } else {
            unsigned char* base = kv8 + ((m == 1) ? 0 : 4);
#pragma unroll
            for (int nt = 0; nt < 2; nt++) {
                int node = n0 + nt * 16 + lr;
                if (node < NN) {
#pragma unroll
                    for (int ct = 0; ct < 4; ct++) {
                        int ch = cmbase + ct * 16 + lc * 4;
                        int wd = __builtin_amdgcn_cvt_pk_fp8_f32(
                            acc[ct][nt][0] + biasv[ct][0],
                            acc[ct][nt][1] + biasv[ct][1], 0, false);
                        wd = __builtin_amdgcn_cvt_pk_fp8_f32(
                            acc[ct][nt][2] + biasv[ct][2],
                            acc[ct][nt][3] + biasv[ct][3], wd, true);
                        *(unsigned int*)(base + (size_t)node * 256 + (ch >> 2) * 8) =
                            (unsigned int)wd;
                    }
                }
            }
        }
    }
}

// ---- fused attention (r14 structure): one wave per node; 4 ch/lane over 32
//      lanes, both halves split the edge list; chunk-16 unchecked + masked
//      tail; beta gate + h update + fused next-layer LN or fused final LN ---
__global__ __launch_bounds__(256) void attn_fused_kernel(const int* __restrict__ off,
                                                         const int* __restrict__ srcs,
                                                         const unsigned short* __restrict__ q,
                                                         const unsigned char* __restrict__ kv8,
                                                         const unsigned short* __restrict__ xrb,
                                                         const float* __restrict__ Wb,
                                                         float* __restrict__ h,
                                                         const float* __restrict__ nsc,
                                                         const float* __restrict__ nbi,
                                                         unsigned short* __restrict__ hn_out,
                                                         const float* __restrict__ fsc,
                                                         const float* __restrict__ fbi,
                                                         float* __restrict__ fout) {
    int wv = threadIdx.x >> 6;    // 4 nodes per block
    int L = threadIdx.x & 63;
    int half = L >> 5, L5 = L & 31;
    int n = blockIdx.x * 4 + wv;
    int o0 = off[n], o1 = off[n + 1];
    int c4 = L5 * 4;
    const float isq = 0.35355339059f;  // 1/sqrt(8)

    ushort4 qu = *(const ushort4*)(q + (size_t)n * DM + c4);
    float q0 = bf2f(qu.x) * isq, q1 = bf2f(qu.y) * isq,
          q2 = bf2f(qu.z) * isq, q3 = bf2f(qu.w) * isq;

    float den = 0.f, a0 = 0.f, a1 = 0.f, a2 = 0.f, a3 = 0.f;
    int p = o0;
    // ---- full chunks: no bounds checks anywhere ----
    for (; p + 16 <= o1; p += 16) {
        int sj[8];
#pragma unroll
        for (int j = 0; j < 8; j++) sj[j] = srcs[p + 2 * j + half];
        uint2 uu[8];
#pragma unroll
        for (int j = 0; j < 8; j++)
            uu[j] = *(const uint2*)(kv8 + (size_t)sj[j] * 256 + L5 * 8);
#pragma unroll
        for (int j = 0; j < 8; j++) {
            f32x2 k01 = __builtin_amdgcn_cvt_pk_f32_fp8(uu[j].x, false);
            f32x2 k23 = __builtin_amdgcn_cvt_pk_f32_fp8(uu[j].x, true);
            f32x2 v01 = __builtin_amdgcn_cvt_pk_f32_fp8(uu[j].y, false);
            f32x2 v23 = __builtin_amdgcn_cvt_pk_f32_fp8(uu[j].y, true);
            float d = q0 * k01.x + q1 * k01.y + q2 * k23.x + q3 * k23.y;
            d += __shfl_xor(d, 1);  // 8-channel head dot (2 lanes/head)
            float e2 = __expf(d);
            den += e2;
            a0 += e2 * v01.x;
            a1 += e2 * v01.y;
            a2 += e2 * v23.x;
            a3 += e2 * v23.y;
        }
    }
    // ---- masked tail chunk (0..15 remaining edges) ----
    if (p < o1) {
        int sj[8];
#pragma unroll
        for (int j = 0; j < 8; j++) {
            int e = p + 2 * j + half;
            sj[j] = (e < o1) ? srcs[e] : 0;
        }
        uint2 uu[8];
#pragma unroll
        for (int j = 0; j < 8; j++)
            uu[j] = *(const uint2*)(kv8 + (size_t)sj[j] * 256 + L5 * 8);
#pragma unroll
        for (int j = 0; j < 8; j++) {
            int e = p + 2 * j + half;
            f32x2 k01 = __builtin_amdgcn_cvt_pk_f32_fp8(uu[j].x, false);
            f32x2 k23 = __builtin_amdgcn_cvt_pk_f32_fp8(uu[j].x, true);
            f32x2 v01 = __builtin_amdgcn_cvt_pk_f32_fp8(uu[j].y, false);
            f32x2 v23 = __builtin_amdgcn_cvt_pk_f32_fp8(uu[j].y, true);
            float d = q0 * k01.x + q1 * k01.y + q2 * k23.x + q3 * k23.y;
            d += __shfl_xor(d, 1);
            float e2 = (e < o1) ? __expf(d) : 0.f;
            den += e2;
            a0 += e2 * v01.x;
            a1 += e2 * v01.y;
            a2 += e2 * v23.x;
            a3 += e2 * v23.y;
        }
    }
    // combine the two half-wave edge partitions (same channels)
    den += __shfl_xor(den, 32);
    a0 += __shfl_xor(a0, 32);
    a1 += __shfl_xor(a1, 32);
    a2 += __shfl_xor(a2, 32);
    a3 += __shfl_xor(a3, 32);

    float inv = (den > 0.f) ? 1.f / den : 0.f;
    float o0v = a0 * inv, o1v = a1 * inv, o2v = a2 * inv, o3v = a3 * inv;

    ushort4 xu = *(const ushort4*)(xrb + (size_t)n * DM + c4);
    float x0 = bf2f(xu.x), x1 = bf2f(xu.y), x2 = bf2f(xu.z), x3 = bf2f(xu.w);
    float c = o0v * Wb[c4] + o1v * Wb[c4 + 1] + o2v * Wb[c4 + 2] + o3v * Wb[c4 + 3]
            + x0 * Wb[DM + c4] + x1 * Wb[DM + c4 + 1]
            + x2 * Wb[DM + c4 + 2] + x3 * Wb[DM + c4 + 3]
            + (o0v - x0) * Wb[2 * DM + c4] + (o1v - x1) * Wb[2 * DM + c4 + 1]
            + (o2v - x2) * Wb[2 * DM + c4 + 2] + (o3v - x3) * Wb[2 * DM + c4 + 3];
    if (half) c = 0.f;   // avoid double-count: channels duplicated across halves
#pragma unroll
    for (int d2 = 32; d2; d2 >>= 1) c += __shfl_xor(c, d2);
    float beta = 1.f / (1.f + __expf(-c));

    size_t idx = (size_t)n * DM + c4;
    float4 hv = *(const float4*)(h + idx);
    hv.x += beta * x0 + (1.f - beta) * o0v;
    hv.y += beta * x1 + (1.f - beta) * o1v;
    hv.z += beta * x2 + (1.f - beta) * o2v;
    hv.w += beta * x3 + (1.f - beta) * o3v;

    if (fout) {
        // final LayerNorm fused -> fp32 d_out
        float s = hv.x + hv.y + hv.z + hv.w;
#pragma unroll
        for (int d2 = 16; d2; d2 >>= 1) s += __shfl_xor(s, d2);
        float mu = s * (1.f / 128.f);
        float d0 = hv.x - mu, d1 = hv.y - mu, d2_ = hv.z - mu, d3 = hv.w - mu;
        float vs = d0 * d0 + d1 * d1 + d2_ * d2_ + d3 * d3;
#pragma unroll
        for (int d2 = 16; d2; d2 >>= 1) vs += __shfl_xor(vs, d2);
        float rstd = rsqrtf(vs * (1.f / 128.f) + 1e-5f);
        if (half == 0) {
            float4 scv = *(const float4*)(fsc + c4);
            float4 biv = *(const float4*)(fbi + c4);
            float4 o;
            o.x = d0 * rstd * scv.x + biv.x;
            o.y = d1 * rstd * scv.y + biv.y;
            o.z = d2_ * rstd * scv.z + biv.z;
            o.w = d3 * rstd * scv.w + biv.w;
            *(float4*)(fout + idx) = o;
        }
    } else {
        if (half == 0) *(float4*)(h + idx) = hv;
        // next-layer LayerNorm fused -> hn bf16
        float s = hv.x + hv.y + hv.z + hv.w;
#pragma unroll
        for (int d2 = 16; d2; d2 >>= 1) s += __shfl_xor(s, d2);
        float mu = s * (1.f / 128.f);
        float d0 = hv.x - mu, d1 = hv.y - mu, d2_ = hv.z - mu, d3 = hv.w - mu;
        float vs = d0 * d0 + d1 * d1 + d2_ * d2_ + d3 * d3;
#pragma unroll
        for (int d2 = 16; d2; d2 >>= 1) vs += __shfl_xor(vs, d2);
        float rstd = rsqrtf(vs * (1.f / 128.f) + 1e-5f);
        if (half == 0) {
            float4 scv = *(const float4*)(nsc + c4);
            float4 biv = *(const float4*)(nbi + c4);
            ushort4 o;
            o.x = f2bf(d0 * rstd * scv.x + biv.x);
            o.y = f2bf(d1 * rstd * scv.y + biv.y);
            o.z = f2bf(d2_ * rstd * scv.z + biv.z);
            o.w = f2bf(d3 * rstd * scv.w + biv.w);
            *(ushort4*)(hn_out + idx) = o;
        }
    }
}

static inline char* alignup(char* p) {
    return (char*)(((uintptr_t)p + 255) & ~(uintptr_t)255);
}

extern "C" void kernel_launch(void* const* d_in, const int* in_sizes, int n_in,
                              void* d_out, int out_size, void* d_ws, size_t ws_size,
                              hipStream_t stream) {
    const float* x       = (const float*)d_in[0];
    const int*   ei      = (const int*)d_in[1];
    const float* W_in    = (const float*)d_in[2];
    const float* b_in    = (const float*)d_in[3];
    const float* in_emb  = (const float*)d_in[4];
    const float* out_emb = (const float*)d_in[5];
    const float* ln_sc   = (const float*)d_in[6];
    const float* ln_bi   = (const float*)d_in[7];
    const float* Wq      = (const float*)d_in[8];
    const float* bq      = (const float*)d_in[9];
    const float* Wk      = (const float*)d_in[10];
    const float* bk      = (const float*)d_in[11];
    const float* Wv      = (const float*)d_in[12];
    const float* bv      = (const float*)d_in[13];
    const float* Wsk     = (const float*)d_in[14];
    const float* bsk     = (const float*)d_in[15];
    const float* Wbeta   = (const float*)d_in[16];
    const float* fn_sc   = (const float*)d_in[17];
    const float* fn_bi   = (const float*)d_in[18];

    char* w = (char*)d_ws;
    int* indeg  = (int*)w; w = alignup(w + (size_t)NN * 4);
    int* outdeg = (int*)w; w = alignup(w + (size_t)NN * 4);
    int* off    = (int*)w; w = alignup(w + (size_t)(NN + 1) * 4);
    int* srcs   = (int*)w; w = alignup(w + (size_t)NE * 4);
    int* tmp    = (int*)w; w = alignup(w + (size_t)NE * 4);
    int* cnt    = (int*)w; w = alignup(w + (size_t)CNTN * 4);
    int* bsum   = (int*)w; w = alignup(w + (size_t)SC1 * 4);
    int* bpre   = (int*)w; w = alignup(w + (size_t)SC1 * 4);
    unsigned int* hpart = (unsigned int*)w; w = alignup(w + (size_t)RNG * REP * 8192 * 4);
    float* h    = (float*)w; w = alignup(w + (size_t)NN * DM * 4);
    unsigned short* hn  = (unsigned short*)w; w = alignup(w + (size_t)NN * DM * 2);
    unsigned short* q   = (unsigned short*)w; w = alignup(w + (size_t)NN * DM * 2);
    unsigned short* xrb = (unsigned short*)w; w = alignup(w + (size_t)NN * DM * 2);
    unsigned char*  kv8 = (unsigned char*)w;  w = alignup(w + (size_t)NN * 256);
    unsigned short* xb  = (unsigned short*)w; w = alignup(w + (size_t)NN * DM * 2);
    unsigned short* Wt  = (unsigned short*)w; w = alignup(w + (size_t)13 * DM * DM * 2);

    // ---- CSR build (no global atomics) ----
    hist_out_kernel<<<dim3(RNG, REP), 1024, 0, stream>>>(ei, hpart);
    hist_reduce_kernel<<<98, 256, 0, stream>>>(hpart, outdeg);
    p1_count_kernel<<<NBLK, 256, 0, stream>>>(ei, cnt);
    gscan1_kernel<<<SC1, 1024, 0, stream>>>(cnt, bsum, CNTN);
    gscan2_kernel<<<1, 1, 0, stream>>>(bsum, bpre, SC1);
    gscan3_kernel<<<SC1, 1024, 0, stream>>>(cnt, bpre, CNTN);
    p3_scatter_kernel<<<NBLK, 256, 0, stream>>>(ei, cnt, tmp);
    p4_fine_kernel<<<NB2, 256, 0, stream>>>(tmp, cnt, off, indeg, srcs);

    wprep_kernel<<<13, 256, 0, stream>>>(Wq, Wk, Wv, Wsk, W_in, Wt);
    xcast_kernel<<<NN * DM / 4 / 256, 256, 0, stream>>>(x, xb);

    gemm_in_mfma<<<391, 256, 0, stream>>>(xb, Wt + (size_t)12 * DM * DM, b_in,
                                          in_emb, out_emb, indeg, outdeg, h,
                                          ln_sc, ln_bi, hn);
    for (int l = 0; l < NL; l++) {
        gemm_qkvs_mfma<<<391, 512, 0, stream>>>(hn,
            Wt + (size_t)l * 4 * DM * DM,
            bq + l * DM, bk + l * DM, bv + l * DM, bsk + l * DM,
            q, kv8, xrb);
        bool last = (l == NL - 1);
        attn_fused_kernel<<<NN / 4, 256, 0, stream>>>(off, srcs, q, kv8, xrb,
            Wbeta + (size_t)l * 3 * DM, h,
            last ? (const float*)nullptr : ln_sc + (l + 1) * DM,
            last ? (const float*)nullptr : ln_bi + (l + 1) * DM,
            last ? (unsigned short*)nullptr : hn,
            last ? fn_sc : (const float*)nullptr,
            last ? fn_bi : (const float*)nullptr,
            last ? (float*)d_out : (float*)nullptr);
    }
}